// Round 13
// baseline (839.464 us; speedup 1.0000x reference)
//
#include <hip/hip_runtime.h>

#define EXPERTS 8
#define HID 2048
#define INTER 4096
#define BTOK 2048
#define NASSIGN 4096   // BTOK * TOPK
#define NTSLOTS 40     // max sum_e ceil(cnt_e/128) = 32+7

typedef float f32x4 __attribute__((ext_vector_type(4)));
typedef __bf16 bf16x8 __attribute__((ext_vector_type(8)));
typedef unsigned short ushortx8 __attribute__((ext_vector_type(8)));

__device__ __forceinline__ unsigned short f2bf(float f) {
  union { float f; unsigned int u; } v; v.f = f;
  unsigned int r = v.u + 0x7fffu + ((v.u >> 16) & 1u);   // RNE
  return (unsigned short)(r >> 16);
}

// ---------------- workspace layout (bytes) ----------------
#define W1T_OFF  0ULL                                   // [E][INTER][HID] bf16 = 128 MiB
#define W3T_OFF  (W1T_OFF + 134217728ULL)               // 128 MiB
#define W2T_OFF  (W3T_OFF + 134217728ULL)               // [E][HID][INTER] bf16 = 128 MiB
#define XB_OFF   (W2T_OFF + 134217728ULL)               // [BTOK][HID] bf16 = 8 MiB
#define GB_OFF   (XB_OFF  + 8388608ULL)                 // [NASSIGN][INTER] bf16 = 32 MiB
#define Y_OFF    (GB_OFF  + 33554432ULL)                // [NASSIGN][HID] f32 = 32 MiB
#define ROWS_OFF (Y_OFF   + 33554432ULL)                // 4096 int
#define OFFS_OFF (ROWS_OFF + 16384ULL)                  // 9 int (padded 64B)
#define TILE_OFF (OFFS_OFF + 64ULL)                     // 40 int

// 64x64 fp32->bf16 transpose tile body (R7-proven, plain loads).
__device__ __forceinline__ void transpose_tile(
    char* pool, const float* __restrict__ src, unsigned short* __restrict__ dst,
    int R, int C, int rt, int ct, int tid)
{
  float (*tile)[65] = (float(*)[65])pool;
  #pragma unroll
  for (int p = 0; p < 4; ++p) {
    int i4 = p * 256 + tid;
    int r = i4 >> 4, c4 = (i4 & 15) << 2;
    float4 v = *(const float4*)&src[(long)(rt * 64 + r) * C + ct * 64 + c4];
    tile[r][c4 + 0] = v.x; tile[r][c4 + 1] = v.y;
    tile[r][c4 + 2] = v.z; tile[r][c4 + 3] = v.w;
  }
  __syncthreads();
  #pragma unroll
  for (int it = 0; it < 2; ++it) {
    int idx = it * 256 + tid;
    int c = idx >> 3, ro = idx & 7;
    union { ushortx8 v; unsigned short s[8]; } pk;
    #pragma unroll
    for (int j = 0; j < 8; ++j) pk.s[j] = f2bf(tile[ro * 8 + j][c]);
    long o = (long)(ct * 64 + c) * R + rt * 64 + ro * 8;
    *(ushortx8*)&dst[o] = pk.v;
  }
}

// ---------------- prep: routing + convert_x + w1/w3 transpose (R7) ----------
__global__ void prep_kernel(const int* __restrict__ eraw,
                            const float* __restrict__ x,
                            const float* __restrict__ w1,
                            const float* __restrict__ w3,
                            unsigned short* __restrict__ xb,
                            unsigned short* __restrict__ w1t,
                            unsigned short* __restrict__ w3t,
                            int* __restrict__ rows, int* __restrict__ offs_g,
                            int* __restrict__ tiles)
{
  __shared__ __align__(16) char pool[16640];
  const int b = blockIdx.x;
  const int tid = threadIdx.x;

  if (b == 0) {
    int* cnt    = (int*)pool;        // 2048
    int* offs_s = cnt + 2048;        // 9
    int* tot    = offs_s + 9;        // 8
    int* found  = tot + 8;           // 1
    if (tid == 0) *found = 0;
    __syncthreads();
    int any = 0;
    for (int j = 0; j < 8; ++j) {
      int a = tid * 8 + j;
      any |= (eraw[2 * a + 1] != 0);
    }
    if (any) atomicOr(found, 1);
    __syncthreads();
    const bool i64 = (*found == 0);
    int lc[8];
    for (int e = 0; e < 8; ++e) lc[e] = 0;
    for (int j = 0; j < 16; ++j) {
      int a = tid * 16 + j;
      int e = i64 ? eraw[2 * a] : eraw[a];
      lc[e]++;
    }
    for (int e = 0; e < 8; ++e) cnt[tid * 8 + e] = lc[e];
    __syncthreads();
    if (tid < 8) {
      int run = 0;
      for (int t = 0; t < 256; ++t) {
        int v = cnt[t * 8 + tid];
        cnt[t * 8 + tid] = run;
        run += v;
      }
      tot[tid] = run;
    }
    __syncthreads();
    if (tid == 0) {
      int o = 0;
      for (int e = 0; e < 8; ++e) { offs_s[e] = o; o += tot[e]; }
      offs_s[8] = o;
      int s = 0;
      for (int e = 0; e < 8; ++e) {
        int nmt = (tot[e] + 127) >> 7;
        for (int m = 0; m < nmt; ++m) tiles[s++] = (e << 16) | m;
      }
      for (; s < NTSLOTS; ++s) tiles[s] = -1;
    }
    __syncthreads();
    if (tid < 9) offs_g[tid] = offs_s[tid];
    int lc2[8];
    for (int e = 0; e < 8; ++e) lc2[e] = 0;
    for (int j = 0; j < 16; ++j) {
      int a = tid * 16 + j;
      int e = i64 ? eraw[2 * a] : eraw[a];
      rows[offs_s[e] + cnt[tid * 8 + e] + lc2[e]] = a;
      lc2[e]++;
    }
  } else if (b < 4097) {
    long idx = (long)(b - 1) * 256 + tid;
    float4 v = *(const float4*)&x[idx * 4];
    unsigned int lo = (unsigned int)f2bf(v.x) | ((unsigned int)f2bf(v.y) << 16);
    unsigned int hi = (unsigned int)f2bf(v.z) | ((unsigned int)f2bf(v.w) << 16);
    uint2 p; p.x = lo; p.y = hi;
    *(uint2*)&xb[idx * 4] = p;
  } else {
    int tb = b - 4097;              // [0, 32768)
    int m16 = tb >> 11;             // 16 matrices (8 w1, 8 w3)
    int rem = tb & 2047;
    int rt = rem >> 6, ct = rem & 63;   // R7 order
    const float* src; unsigned short* dst;
    if (m16 < 8) { src = w1 + (long)m16 * HID * INTER;       dst = w1t + (long)m16 * INTER * HID; }
    else         { src = w3 + (long)(m16 - 8) * HID * INTER; dst = w3t + (long)(m16 - 8) * INTER * HID; }
    transpose_tile(pool, src, dst, HID, INTER, rt, ct, tid);
  }
}

// ---------------- fused: w2 transpose ∥ gate+up GEMM ------------------------
// counted-vmcnt depth-2 (R11) + SEG-MAJOR LDS: tiles stored [k8][rows][8] so
// a frag read's 16 row-lanes cover 16B-contiguous LDS (2-way banks, free)
// instead of 64B-strided rows (8 dwords/bank serialization). gload_lds dest
// stays linear; the permutation lives in the per-thread GLOBAL src assignment.
__global__ __launch_bounds__(256, 3) void fused_w2t_gateup(
    const float* __restrict__ w2,
    unsigned short* __restrict__ w2t,
    const unsigned short* __restrict__ xb,
    const unsigned short* __restrict__ w1t,
    const unsigned short* __restrict__ w3t,
    unsigned short* __restrict__ gb,
    const int* __restrict__ rows,
    const int* __restrict__ offs,
    const int* __restrict__ tiles)
{
  __shared__ __align__(16) char pool[49152];
  const int b = blockIdx.x;
  const int tid = threadIdx.x;
  const int q = b / 7, r = b - q * 7;

  if (!(r == 0 && q < 2560)) {
    int ng = (b + 6) / 7; if (ng > 2560) ng = 2560;
    int ti = b - ng;                 // [0, 16384)
    int e = ti >> 11;
    int rem = ti & 2047;
    int rt = rem >> 5, ct = rem & 31;
    transpose_tile(pool, w2 + (long)e * INTER * HID, w2t + (long)e * HID * INTER,
                   INTER, HID, rt, ct, tid);
    return;
  }

  const int slot = q >> 6;
  const int nt   = q & 63;
  const int te = tiles[slot];
  if (te < 0) return;
  const int e  = te >> 16, mt = te & 0xffff;
  const int off = offs[e];
  const int cnt = offs[e + 1] - off;

  unsigned short* As  = (unsigned short*)pool;            // [3][4][128][8] = 24 KiB
  unsigned short* B1s = (unsigned short*)(pool + 24576);  // [3][4][64][8]  = 12 KiB
  unsigned short* B3s = (unsigned short*)(pool + 36864);  // [3][4][64][8]  = 12 KiB

  const int lane = tid & 63;
  const int wave = tid >> 6;
  const int wr = wave >> 1, wc = wave & 1;

  // A: seg-major. idx = tid + 256c -> (seg = idx>>7, row = idx&127);
  // LDS elem offset = idx*8 (linear in tid: gload_lds-legal).
  const unsigned short* aptr[2];
  #pragma unroll
  for (int c = 0; c < 2; ++c) {
    int idx = tid + c * 256;
    int row = idx & 127, seg = idx >> 7;
    int rr = off + mt * 128 + row;
    int rv = (rr < off + cnt) ? rr : (off + cnt - 1);
    long tok = rows[rv] >> 1;
    aptr[c] = xb + tok * HID + seg * 8;
  }
  // B: seg-major. tid -> (seg = tid>>6, row = tid&63); LDS elem = tid*8.
  const unsigned short* b1p;
  const unsigned short* b3p;
  {
    int row = tid & 63, seg = tid >> 6;
    b1p = w1t + ((long)e * INTER + nt * 64 + row) * HID + seg * 8;
    b3p = w3t + ((long)e * INTER + nt * 64 + row) * HID + seg * 8;
  }

  auto STAGE = [&](int buf, int k0) {   // 4 VMEM loads per call
    #pragma unroll
    for (int c = 0; c < 2; ++c)
      __builtin_amdgcn_global_load_lds(
          (const __attribute__((address_space(1))) unsigned int*)(aptr[c] + k0),
          (__attribute__((address_space(3))) unsigned int*)(&As[buf * 4096 + (tid + c * 256) * 8]),
          16, 0, 0);
    __builtin_amdgcn_global_load_lds(
        (const __attribute__((address_space(1))) unsigned int*)(b1p + k0),
        (__attribute__((address_space(3))) unsigned int*)(&B1s[buf * 2048 + tid * 8]),
        16, 0, 0);
    __builtin_amdgcn_global_load_lds(
        (const __attribute__((address_space(1))) unsigned int*)(b3p + k0),
        (__attribute__((address_space(3))) unsigned int*)(&B3s[buf * 2048 + tid * 8]),
        16, 0, 0);
  };

  f32x4 acc1[4][2], acc3[4][2];
  #pragma unroll
  for (int i = 0; i < 4; ++i)
    #pragma unroll
    for (int j = 0; j < 2; ++j) { acc1[i][j] = (f32x4)0.0f; acc3[i][j] = (f32x4)0.0f; }

  STAGE(0, 0);
  STAGE(1, 32);
  const int NIT = HID / 32;   // 64
  for (int t = 0; t < NIT; ++t) {
    if (t == NIT - 1) asm volatile("s_waitcnt vmcnt(0)" ::: "memory");
    else              asm volatile("s_waitcnt vmcnt(4)" ::: "memory");
    __builtin_amdgcn_s_barrier();
    asm volatile("" ::: "memory");
    if (t + 2 < NIT) STAGE((t + 2) % 3, (t + 2) * 32);
    const int cur = t % 3;
    const int k8 = lane >> 4;
    bf16x8 af[4], b1f[2], b3f[2];
    #pragma unroll
    for (int f = 0; f < 4; ++f)
      af[f] = __builtin_bit_cast(bf16x8, *(const ushortx8*)&As[cur * 4096 + (k8 * 128 + wr * 64 + f * 16 + (lane & 15)) * 8]);
    #pragma unroll
    for (int j = 0; j < 2; ++j) {
      b1f[j] = __builtin_bit_cast(bf16x8, *(const ushortx8*)&B1s[cur * 2048 + (k8 * 64 + wc * 32 + j * 16 + (lane & 15)) * 8]);
      b3f[j] = __builtin_bit_cast(bf16x8, *(const ushortx8*)&B3s[cur * 2048 + (k8 * 64 + wc * 32 + j * 16 + (lane & 15)) * 8]);
    }
    #pragma unroll
    for (int i = 0; i < 4; ++i)
      #pragma unroll
      for (int j = 0; j < 2; ++j) {
        acc1[i][j] = __builtin_amdgcn_mfma_f32_16x16x32_bf16(af[i], b1f[j], acc1[i][j], 0, 0, 0);
        acc3[i][j] = __builtin_amdgcn_mfma_f32_16x16x32_bf16(af[i], b3f[j], acc3[i][j], 0, 0, 0);
      }
  }

  const int rtop = off + cnt;
  const int grb  = off + mt * 128 + wr * 64;
  const int gcb  = nt * 64 + wc * 32;
  #pragma unroll
  for (int i = 0; i < 4; ++i) {
    #pragma unroll
    for (int j = 0; j < 2; ++j) {
      int gc = gcb + j * 16 + (lane & 15);
      #pragma unroll
      for (int qq = 0; qq < 4; ++qq) {
        int gr = grb + i * 16 + (lane >> 4) * 4 + qq;
        if (gr < rtop) {
          float g = acc1[i][j][qq];
          float u = acc3[i][j][qq];
          float s = g / (1.0f + __expf(-g));
          gb[(long)gr * INTER + gc] = f2bf(s * u);
        }
      }
    }
  }
}

// ---------------- down grouped GEMM, counted-vmcnt + seg-major LDS ----------
__global__ __launch_bounds__(256, 4) void gemm_down(
    const unsigned short* __restrict__ gbin,
    const unsigned short* __restrict__ w2t,
    float* __restrict__ y,
    const int* __restrict__ rows,
    const int* __restrict__ offs,
    const int* __restrict__ tiles)
{
  const int te = tiles[blockIdx.y];
  if (te < 0) return;
  const int e  = te >> 16, mt = te & 0xffff;
  const int off = offs[e];
  const int cnt = offs[e + 1] - off;
  const int nt  = blockIdx.x;                 // 32 N-tiles of 64 over HID

  __shared__ __align__(16) unsigned short As[3][4 * 128 * 8];  // 24 KiB
  __shared__ __align__(16) unsigned short Bs[3][4 * 64 * 8];   // 12 KiB

  const int tid  = threadIdx.x;
  const int lane = tid & 63;
  const int wave = tid >> 6;
  const int wr = wave >> 1, wc = wave & 1;

  const unsigned short* aptr[2];
  #pragma unroll
  for (int c = 0; c < 2; ++c) {
    int idx = tid + c * 256;
    int row = idx & 127, seg = idx >> 7;
    int rr = off + mt * 128 + row;
    int rv = (rr < off + cnt) ? rr : (off + cnt - 1);
    aptr[c] = gbin + (long)rv * INTER + seg * 8;
  }
  const unsigned short* bp;
  {
    int row = tid & 63, seg = tid >> 6;
    bp = w2t + ((long)e * HID + nt * 64 + row) * INTER + seg * 8;
  }

  auto STAGE = [&](int buf, int k0) {   // 3 VMEM loads per call
    #pragma unroll
    for (int c = 0; c < 2; ++c)
      __builtin_amdgcn_global_load_lds(
          (const __attribute__((address_space(1))) unsigned int*)(aptr[c] + k0),
          (__attribute__((address_space(3))) unsigned int*)(&As[buf][(tid + c * 256) * 8]),
          16, 0, 0);
    __builtin_amdgcn_global_load_lds(
        (const __attribute__((address_space(1))) unsigned int*)(bp + k0),
        (__attribute__((address_space(3))) unsigned int*)(&Bs[buf][tid * 8]),
        16, 0, 0);
  };

  f32x4 acc[4][2];
  #pragma unroll
  for (int i = 0; i < 4; ++i)
    #pragma unroll
    for (int j = 0; j < 2; ++j) acc[i][j] = (f32x4)0.0f;

  STAGE(0, 0);
  STAGE(1, 32);
  const int NIT = INTER / 32;   // 128
  for (int t = 0; t < NIT; ++t) {
    if (t == NIT - 1) asm volatile("s_waitcnt vmcnt(0)" ::: "memory");
    else              asm volatile("s_waitcnt vmcnt(3)" ::: "memory");
    __builtin_amdgcn_s_barrier();
    asm volatile("" ::: "memory");
    if (t + 2 < NIT) STAGE((t + 2) % 3, (t + 2) * 32);
    const int cur = t % 3;
    const int k8 = lane >> 4;
    bf16x8 af[4], bf[2];
    #pragma unroll
    for (int f = 0; f < 4; ++f)
      af[f] = __builtin_bit_cast(bf16x8, *(const ushortx8*)&As[cur][(k8 * 128 + wr * 64 + f * 16 + (lane & 15)) * 8]);
    #pragma unroll
    for (int j = 0; j < 2; ++j)
      bf[j] = __builtin_bit_cast(bf16x8, *(const ushortx8*)&Bs[cur][(k8 * 64 + wc * 32 + j * 16 + (lane & 15)) * 8]);
    #pragma unroll
    for (int i = 0; i < 4; ++i)
      #pragma unroll
      for (int j = 0; j < 2; ++j)
        acc[i][j] = __builtin_amdgcn_mfma_f32_16x16x32_bf16(af[i], bf[j], acc[i][j], 0, 0, 0);
  }

  const int rtop = off + cnt;
  const int grb  = off + mt * 128 + wr * 64;
  const int gcb  = nt * 64 + wc * 32;
  #pragma unroll
  for (int i = 0; i < 4; ++i) {
    #pragma unroll
    for (int j = 0; j < 2; ++j) {
      int gc = gcb + j * 16 + (lane & 15);
      #pragma unroll
      for (int q = 0; q < 4; ++q) {
        int gr = grb + i * 16 + (lane >> 4) * 4 + q;
        if (gr < rtop) {
          int a = rows[gr];
          y[(long)a * HID + gc] = acc[i][j][q];
        }
      }
    }
  }
}

// ---------------- combine: out[t] = ew0*Y[2t] + ew1*Y[2t+1] ----------------
__global__ void combine_kernel(const float* __restrict__ Y,
                               const float* __restrict__ ew,
                               float* __restrict__ out)
{
  int idx = blockIdx.x * 256 + threadIdx.x;
  int t = idx >> 9;
  int h = (idx & 511) * 4;
  float w0 = ew[2 * t], w1 = ew[2 * t + 1];
  float4 y0 = *(const float4*)&Y[(long)(2 * t) * HID + h];
  float4 y1 = *(const float4*)&Y[(long)(2 * t + 1) * HID + h];
  float4 o;
  o.x = w0 * y0.x + w1 * y1.x;
  o.y = w0 * y0.y + w1 * y1.y;
  o.z = w0 * y0.z + w1 * y1.z;
  o.w = w0 * y0.w + w1 * y1.w;
  *(float4*)&out[(long)t * HID + h] = o;
}

extern "C" void kernel_launch(void* const* d_in, const int* in_sizes, int n_in,
                              void* d_out, int out_size, void* d_ws, size_t ws_size,
                              hipStream_t stream) {
  const float* x   = (const float*)d_in[0];
  const int*   eix = (const int*)d_in[1];
  const float* ew  = (const float*)d_in[2];
  const float* w1  = (const float*)d_in[3];
  const float* w2  = (const float*)d_in[4];
  const float* w3  = (const float*)d_in[5];
  float* out = (float*)d_out;

  char* ws = (char*)d_ws;
  unsigned short* w1t = (unsigned short*)(ws + W1T_OFF);
  unsigned short* w3t = (unsigned short*)(ws + W3T_OFF);
  unsigned short* w2t = (unsigned short*)(ws + W2T_OFF);
  unsigned short* xb  = (unsigned short*)(ws + XB_OFF);
  unsigned short* gb  = (unsigned short*)(ws + GB_OFF);
  float*          y   = (float*)(ws + Y_OFF);
  int*            rows  = (int*)(ws + ROWS_OFF);
  int*            offs  = (int*)(ws + OFFS_OFF);
  int*            tiles = (int*)(ws + TILE_OFF);

  prep_kernel<<<36865, 256, 0, stream>>>(eix, x, w1, w3, xb, w1t, w3t,
                                         rows, offs, tiles);
  fused_w2t_gateup<<<18944, 256, 0, stream>>>(w2, w2t, xb, w1t, w3t,
                                              gb, rows, offs, tiles);
  gemm_down<<<dim3(HID / 64, NTSLOTS), 256, 0, stream>>>(
      gb, w2t, y, rows, offs, tiles);
  combine_kernel<<<4096, 256, 0, stream>>>(y, ew, out);
}

// Round 14
// 554.618 us; speedup vs baseline: 1.5136x; 1.5136x over previous
//
#include <hip/hip_runtime.h>

#define EXPERTS 8
#define HID 2048
#define INTER 4096
#define BTOK 2048
#define NASSIGN 4096   // BTOK * TOPK
#define NTSLOTS 40     // max sum_e ceil(cnt_e/128) = 32+7

typedef float f32x4 __attribute__((ext_vector_type(4)));
typedef __bf16 bf16x8 __attribute__((ext_vector_type(8)));
typedef unsigned short ushortx8 __attribute__((ext_vector_type(8)));

__device__ __forceinline__ unsigned short f2bf(float f) {
  union { float f; unsigned int u; } v; v.f = f;
  unsigned int r = v.u + 0x7fffu + ((v.u >> 16) & 1u);   // RNE
  return (unsigned short)(r >> 16);
}

// ---------------- workspace layout (bytes) ----------------
#define XB_OFF   0ULL                                   // [BTOK][HID] bf16 = 8 MiB
#define GB_OFF   (XB_OFF + 8388608ULL)                  // [NASSIGN][INTER] bf16 = 32 MiB
#define Y_OFF    (GB_OFF + 33554432ULL)                 // [NASSIGN][HID] f32 = 32 MiB
#define ROWS_OFF (Y_OFF  + 33554432ULL)                 // 4096 int
#define OFFS_OFF (ROWS_OFF + 16384ULL)                  // 9 int (padded 64B)
#define TILE_OFF (OFFS_OFF + 64ULL)                     // 40 int

// ---------------- prep: routing (block 0) + x f32->bf16 ----------------
__global__ void prep_kernel(const int* __restrict__ eraw,
                            const float* __restrict__ x,
                            unsigned short* __restrict__ xb,
                            int* __restrict__ rows, int* __restrict__ offs_g,
                            int* __restrict__ tiles)
{
  const int b = blockIdx.x;
  const int tid = threadIdx.x;

  if (b == 0) {
    __shared__ int cnt[256 * 8];
    __shared__ int offs_s[9];
    __shared__ int tot[8];
    __shared__ int found_odd;
    if (tid == 0) found_odd = 0;
    __syncthreads();
    int any = 0;
    for (int j = 0; j < 8; ++j) {
      int a = tid * 8 + j;
      any |= (eraw[2 * a + 1] != 0);
    }
    if (any) atomicOr(&found_odd, 1);
    __syncthreads();
    const bool i64 = (found_odd == 0);
    int lc[8];
    for (int e = 0; e < 8; ++e) lc[e] = 0;
    for (int j = 0; j < 16; ++j) {
      int a = tid * 16 + j;
      int e = i64 ? eraw[2 * a] : eraw[a];
      lc[e]++;
    }
    for (int e = 0; e < 8; ++e) cnt[tid * 8 + e] = lc[e];
    __syncthreads();
    if (tid < 8) {
      int run = 0;
      for (int t = 0; t < 256; ++t) {
        int v = cnt[t * 8 + tid];
        cnt[t * 8 + tid] = run;
        run += v;
      }
      tot[tid] = run;
    }
    __syncthreads();
    if (tid == 0) {
      int o = 0;
      for (int e = 0; e < 8; ++e) { offs_s[e] = o; o += tot[e]; }
      offs_s[8] = o;
      int s = 0;
      for (int e = 0; e < 8; ++e) {
        int nmt = (tot[e] + 127) >> 7;
        for (int m = 0; m < nmt; ++m) tiles[s++] = (e << 16) | m;
      }
      for (; s < NTSLOTS; ++s) tiles[s] = -1;
    }
    __syncthreads();
    if (tid < 9) offs_g[tid] = offs_s[tid];
    int lc2[8];
    for (int e = 0; e < 8; ++e) lc2[e] = 0;
    for (int j = 0; j < 16; ++j) {
      int a = tid * 16 + j;
      int e = i64 ? eraw[2 * a] : eraw[a];
      rows[offs_s[e] + cnt[tid * 8 + e] + lc2[e]] = a;
      lc2[e]++;
    }
  } else {
    long idx = (long)(b - 1) * 256 + tid;
    float4 v = *(const float4*)&x[idx * 4];
    unsigned int lo = (unsigned int)f2bf(v.x) | ((unsigned int)f2bf(v.y) << 16);
    unsigned int hi = (unsigned int)f2bf(v.z) | ((unsigned int)f2bf(v.w) << 16);
    uint2 p; p.x = lo; p.y = hi;
    *(uint2*)&xb[idx * 4] = p;
  }
}

// ---------------- gate+up grouped GEMM, direct fp32 weights -----------------
// Per K-iter: stage raw fp32 B [32k][64n] via gload_lds (coalesced, linear),
// cooperative convert-transpose to bf16 Bbf [k8][64n][8] (2-way reads = free,
// b128 writes at minimum 8-phase aliasing), MFMA. A = xb bf16, R11 layout.
// LDS 40 KiB -> 4 blocks/CU.
__global__ __launch_bounds__(256, 4) void gemm_gateup(
    const unsigned short* __restrict__ xb,
    const float* __restrict__ w1,
    const float* __restrict__ w3,
    unsigned short* __restrict__ gb,
    const int* __restrict__ rows,
    const int* __restrict__ offs,
    const int* __restrict__ tiles)
{
  const int te = tiles[blockIdx.y];
  if (te < 0) return;
  const int e  = te >> 16, mt = te & 0xffff;
  const int off = offs[e];
  const int cnt = offs[e + 1] - off;
  const int nt  = blockIdx.x;                 // 64 N-tiles of 64 over INTER

  __shared__ __align__(16) unsigned short As[2][128 * 32];   // 16 KiB
  __shared__ __align__(16) float B1raw[32 * 64];             //  8 KiB
  __shared__ __align__(16) float B3raw[32 * 64];             //  8 KiB
  __shared__ __align__(16) unsigned short B1bf[4 * 64 * 8];  //  4 KiB
  __shared__ __align__(16) unsigned short B3bf[4 * 64 * 8];  //  4 KiB

  const int tid  = threadIdx.x;
  const int lane = tid & 63;
  const int wave = tid >> 6;
  const int wr = wave >> 1, wc = wave & 1;

  // A staging (R11-proven): idx -> (row=idx>>2, seg=idx&3), LDS linear.
  const unsigned short* aptr[2];
  #pragma unroll
  for (int c = 0; c < 2; ++c) {
    int idx = tid + c * 256;
    int row = idx >> 2, seg = idx & 3;
    int rr = off + mt * 128 + row;
    int rv = (rr < off + cnt) ? rr : (off + cnt - 1);
    long tok = rows[rv] >> 1;
    aptr[c] = xb + tok * HID + seg * 8;
  }
  // B staging: chunk c covers k-rows [c*16, c*16+16); 16 threads/row.
  const float* b1p[2];
  const float* b3p[2];
  #pragma unroll
  for (int c = 0; c < 2; ++c) {
    int k = (tid >> 4) + c * 16, n4 = (tid & 15) * 4;
    b1p[c] = w1 + ((long)e * HID + k) * INTER + nt * 64 + n4;
    b3p[c] = w3 + ((long)e * HID + k) * INTER + nt * 64 + n4;
  }

  auto STAGE = [&](int abuf, long koff32) {   // 6 VMEM ops
    #pragma unroll
    for (int c = 0; c < 2; ++c) {
      __builtin_amdgcn_global_load_lds(
          (const __attribute__((address_space(1))) unsigned int*)(aptr[c] + koff32),
          (__attribute__((address_space(3))) unsigned int*)(&As[abuf][(tid + c * 256) * 8]),
          16, 0, 0);
      __builtin_amdgcn_global_load_lds(
          (const __attribute__((address_space(1))) unsigned int*)(b1p[c] + koff32 * INTER),
          (__attribute__((address_space(3))) unsigned int*)(&B1raw[(tid + c * 256) * 4]),
          16, 0, 0);
      __builtin_amdgcn_global_load_lds(
          (const __attribute__((address_space(1))) unsigned int*)(b3p[c] + koff32 * INTER),
          (__attribute__((address_space(3))) unsigned int*)(&B3raw[(tid + c * 256) * 4]),
          16, 0, 0);
    }
  };

  f32x4 acc1[4][2], acc3[4][2];
  #pragma unroll
  for (int i = 0; i < 4; ++i)
    #pragma unroll
    for (int j = 0; j < 2; ++j) { acc1[i][j] = (f32x4)0.0f; acc3[i][j] = (f32x4)0.0f; }

  STAGE(0, 0);
  const int NIT = HID / 32;   // 64
  const int cn = tid & 63, ck8 = tid >> 6;   // convert-role: column n, k-oct
  for (int t = 0; t < NIT; ++t) {
    asm volatile("s_waitcnt vmcnt(0)" ::: "memory");
    __builtin_amdgcn_s_barrier();
    asm volatile("" ::: "memory");
    // convert-transpose B(t): Braw[k][n] -> Bbf[k8][n][8]
    {
      union { ushortx8 v; unsigned short s[8]; } p1, p3;
      #pragma unroll
      for (int j = 0; j < 8; ++j) {
        p1.s[j] = f2bf(B1raw[(ck8 * 8 + j) * 64 + cn]);
        p3.s[j] = f2bf(B3raw[(ck8 * 8 + j) * 64 + cn]);
      }
      *(ushortx8*)&B1bf[(ck8 * 64 + cn) * 8] = p1.v;
      *(ushortx8*)&B3bf[(ck8 * 64 + cn) * 8] = p3.v;
    }
    __syncthreads();   // Bbf ready; Braw consumed
    if (t + 1 < NIT) STAGE((t + 1) & 1, (long)(t + 1) * 32);
    const int cur = t & 1;
    const int k8 = lane >> 4;
    bf16x8 af[4], b1f[2], b3f[2];
    #pragma unroll
    for (int f = 0; f < 4; ++f)
      af[f] = __builtin_bit_cast(bf16x8, *(const ushortx8*)&As[cur][(wr * 64 + f * 16 + (lane & 15)) * 32 + k8 * 8]);
    #pragma unroll
    for (int j = 0; j < 2; ++j) {
      b1f[j] = __builtin_bit_cast(bf16x8, *(const ushortx8*)&B1bf[(k8 * 64 + wc * 32 + j * 16 + (lane & 15)) * 8]);
      b3f[j] = __builtin_bit_cast(bf16x8, *(const ushortx8*)&B3bf[(k8 * 64 + wc * 32 + j * 16 + (lane & 15)) * 8]);
    }
    #pragma unroll
    for (int i = 0; i < 4; ++i)
      #pragma unroll
      for (int j = 0; j < 2; ++j) {
        acc1[i][j] = __builtin_amdgcn_mfma_f32_16x16x32_bf16(af[i], b1f[j], acc1[i][j], 0, 0, 0);
        acc3[i][j] = __builtin_amdgcn_mfma_f32_16x16x32_bf16(af[i], b3f[j], acc3[i][j], 0, 0, 0);
      }
  }

  const int rtop = off + cnt;
  const int grb  = off + mt * 128 + wr * 64;
  const int gcb  = nt * 64 + wc * 32;
  #pragma unroll
  for (int i = 0; i < 4; ++i) {
    #pragma unroll
    for (int j = 0; j < 2; ++j) {
      int gc = gcb + j * 16 + (lane & 15);
      #pragma unroll
      for (int qq = 0; qq < 4; ++qq) {
        int gr = grb + i * 16 + (lane >> 4) * 4 + qq;
        if (gr < rtop) {
          float g = acc1[i][j][qq];
          float u = acc3[i][j][qq];
          float s = g / (1.0f + __expf(-g));
          gb[(long)gr * INTER + gc] = f2bf(s * u);
        }
      }
    }
  }
}

// ---------------- down grouped GEMM, direct fp32 w2 ------------------------
// Same inline convert-transpose. LDS 28 KiB -> 5 blocks/CU.
__global__ __launch_bounds__(256, 4) void gemm_down(
    const unsigned short* __restrict__ gbin,
    const float* __restrict__ w2,
    float* __restrict__ y,
    const int* __restrict__ rows,
    const int* __restrict__ offs,
    const int* __restrict__ tiles)
{
  const int te = tiles[blockIdx.y];
  if (te < 0) return;
  const int e  = te >> 16, mt = te & 0xffff;
  const int off = offs[e];
  const int cnt = offs[e + 1] - off;
  const int nt  = blockIdx.x;                 // 32 N-tiles of 64 over HID

  __shared__ __align__(16) unsigned short As[2][128 * 32];   // 16 KiB
  __shared__ __align__(16) float Braw[32 * 64];              //  8 KiB
  __shared__ __align__(16) unsigned short Bbf[4 * 64 * 8];   //  4 KiB

  const int tid  = threadIdx.x;
  const int lane = tid & 63;
  const int wave = tid >> 6;
  const int wr = wave >> 1, wc = wave & 1;

  const unsigned short* aptr[2];
  #pragma unroll
  for (int c = 0; c < 2; ++c) {
    int idx = tid + c * 256;
    int row = idx >> 2, seg = idx & 3;
    int rr = off + mt * 128 + row;
    int rv = (rr < off + cnt) ? rr : (off + cnt - 1);
    aptr[c] = gbin + (long)rv * INTER + seg * 8;
  }
  const float* bp[2];
  #pragma unroll
  for (int c = 0; c < 2; ++c) {
    int k = (tid >> 4) + c * 16, n4 = (tid & 15) * 4;
    bp[c] = w2 + ((long)e * INTER + k) * HID + nt * 64 + n4;
  }

  auto STAGE = [&](int abuf, long koff32) {   // 4 VMEM ops
    #pragma unroll
    for (int c = 0; c < 2; ++c) {
      __builtin_amdgcn_global_load_lds(
          (const __attribute__((address_space(1))) unsigned int*)(aptr[c] + koff32),
          (__attribute__((address_space(3))) unsigned int*)(&As[abuf][(tid + c * 256) * 8]),
          16, 0, 0);
      __builtin_amdgcn_global_load_lds(
          (const __attribute__((address_space(1))) unsigned int*)(bp[c] + koff32 * HID),
          (__attribute__((address_space(3))) unsigned int*)(&Braw[(tid + c * 256) * 4]),
          16, 0, 0);
    }
  };

  f32x4 acc[4][2];
  #pragma unroll
  for (int i = 0; i < 4; ++i)
    #pragma unroll
    for (int j = 0; j < 2; ++j) acc[i][j] = (f32x4)0.0f;

  STAGE(0, 0);
  const int NIT = INTER / 32;   // 128
  const int cn = tid & 63, ck8 = tid >> 6;
  for (int t = 0; t < NIT; ++t) {
    asm volatile("s_waitcnt vmcnt(0)" ::: "memory");
    __builtin_amdgcn_s_barrier();
    asm volatile("" ::: "memory");
    {
      union { ushortx8 v; unsigned short s[8]; } pk;
      #pragma unroll
      for (int j = 0; j < 8; ++j)
        pk.s[j] = f2bf(Braw[(ck8 * 8 + j) * 64 + cn]);
      *(ushortx8*)&Bbf[(ck8 * 64 + cn) * 8] = pk.v;
    }
    __syncthreads();
    if (t + 1 < NIT) STAGE((t + 1) & 1, (long)(t + 1) * 32);
    const int cur = t & 1;
    const int k8 = lane >> 4;
    bf16x8 af[4], bf[2];
    #pragma unroll
    for (int f = 0; f < 4; ++f)
      af[f] = __builtin_bit_cast(bf16x8, *(const ushortx8*)&As[cur][(wr * 64 + f * 16 + (lane & 15)) * 32 + k8 * 8]);
    #pragma unroll
    for (int j = 0; j < 2; ++j)
      bf[j] = __builtin_bit_cast(bf16x8, *(const ushortx8*)&Bbf[(k8 * 64 + wc * 32 + j * 16 + (lane & 15)) * 8]);
    #pragma unroll
    for (int i = 0; i < 4; ++i)
      #pragma unroll
      for (int j = 0; j < 2; ++j)
        acc[i][j] = __builtin_amdgcn_mfma_f32_16x16x32_bf16(af[i], bf[j], acc[i][j], 0, 0, 0);
  }

  const int rtop = off + cnt;
  const int grb  = off + mt * 128 + wr * 64;
  const int gcb  = nt * 64 + wc * 32;
  #pragma unroll
  for (int i = 0; i < 4; ++i) {
    #pragma unroll
    for (int j = 0; j < 2; ++j) {
      int gc = gcb + j * 16 + (lane & 15);
      #pragma unroll
      for (int q = 0; q < 4; ++q) {
        int gr = grb + i * 16 + (lane >> 4) * 4 + q;
        if (gr < rtop) {
          int a = rows[gr];
          y[(long)a * HID + gc] = acc[i][j][q];
        }
      }
    }
  }
}

// ---------------- combine: out[t] = ew0*Y[2t] + ew1*Y[2t+1] ----------------
__global__ void combine_kernel(const float* __restrict__ Y,
                               const float* __restrict__ ew,
                               float* __restrict__ out)
{
  int idx = blockIdx.x * 256 + threadIdx.x;
  int t = idx >> 9;
  int h = (idx & 511) * 4;
  float w0 = ew[2 * t], w1 = ew[2 * t + 1];
  float4 y0 = *(const float4*)&Y[(long)(2 * t) * HID + h];
  float4 y1 = *(const float4*)&Y[(long)(2 * t + 1) * HID + h];
  float4 o;
  o.x = w0 * y0.x + w1 * y1.x;
  o.y = w0 * y0.y + w1 * y1.y;
  o.z = w0 * y0.z + w1 * y1.z;
  o.w = w0 * y0.w + w1 * y1.w;
  *(float4*)&out[(long)t * HID + h] = o;
}

extern "C" void kernel_launch(void* const* d_in, const int* in_sizes, int n_in,
                              void* d_out, int out_size, void* d_ws, size_t ws_size,
                              hipStream_t stream) {
  const float* x   = (const float*)d_in[0];
  const int*   eix = (const int*)d_in[1];
  const float* ew  = (const float*)d_in[2];
  const float* w1  = (const float*)d_in[3];
  const float* w2  = (const float*)d_in[4];
  const float* w3  = (const float*)d_in[5];
  float* out = (float*)d_out;

  char* ws = (char*)d_ws;
  unsigned short* xb  = (unsigned short*)(ws + XB_OFF);
  unsigned short* gb  = (unsigned short*)(ws + GB_OFF);
  float*          y   = (float*)(ws + Y_OFF);
  int*            rows  = (int*)(ws + ROWS_OFF);
  int*            offs  = (int*)(ws + OFFS_OFF);
  int*            tiles = (int*)(ws + TILE_OFF);

  prep_kernel<<<4097, 256, 0, stream>>>(eix, x, xb, rows, offs, tiles);
  gemm_gateup<<<dim3(INTER / 64, NTSLOTS), 256, 0, stream>>>(
      xb, w1, w3, gb, rows, offs, tiles);
  gemm_down<<<dim3(HID / 64, NTSLOTS), 256, 0, stream>>>(
      gb, w2, y, rows, offs, tiles);
  combine_kernel<<<4096, 256, 0, stream>>>(y, ew, out);
}